// Round 7
// baseline (267.048 us; speedup 1.0000x reference)
//
#include <hip/hip_runtime.h>

// QuantumClassicalInterface on MI355X (gfx950). Round 15.
// f32 I/O. prep: cls/qnt -> bf16, Wc/Wq -> bf16, Wg -> fp8, l -> 0.
// Projections: bf16 MFMA (128^2, BK=64, XOR swizzle, counted-vmcnt dbuf).
// Gate/Sim/PV: MX-scaled fp8 MFMA (16x16x128, unit scales), 128^2 single-buf
// 32KB (5 blocks/CU TLP — the measured optimum for this latency-bound shape).
// R15: (a) sim epilogue: LDS-staged coalesced C-store (was 64x 1-byte scattered
// stores/thread -> now 64B/lane dwordx4), bank-spread via row-keyed XOR;
// (b) transpose_fp8 vectorized (short8 loads + cvt_pk + 16B stores);
// (c) scaled-MFMA frags built in place (no shufflevector copies).
// Softmax fused (exp + atomic row sums; logits bounded so no max-sub needed).
// PV epilogue does final merge: out = classical + g * (P@quantum)/l.

typedef unsigned short u16;
typedef unsigned char u8;
typedef __bf16 bf16x8 __attribute__((ext_vector_type(8)));
typedef float f32x4 __attribute__((ext_vector_type(4)));
typedef int i32x4 __attribute__((ext_vector_type(4)));
typedef int i32x8 __attribute__((ext_vector_type(8)));
typedef short short8 __attribute__((ext_vector_type(8)));

__device__ __forceinline__ u16 f2bf(float f) {
    unsigned int x;
    __builtin_memcpy(&x, &f, 4);
    unsigned int r = x + 0x7FFFu + ((x >> 16) & 1u);
    return (u16)(r >> 16);
}
__device__ __forceinline__ float bf2f(u16 u) {
    unsigned int x = ((unsigned int)u) << 16;
    float f;
    __builtin_memcpy(&f, &x, 4);
    return f;
}
__device__ __forceinline__ u8 f2fp8(float f) {
    int p = __builtin_amdgcn_cvt_pk_fp8_f32(f, f, 0, false);
    return (u8)(p & 0xFF);
}

// XCD-aware bijective swizzle of the (x,y) tile space (nwg % 8 == 0 here).
__device__ __forceinline__ void xcd_tile(int& tx, int& ty) {
    const int gx = gridDim.x;
    const int nwg = gx * gridDim.y;
    const int l = blockIdx.x + gx * blockIdx.y;
    const int per = nwg >> 3;
    const int swz = (l & 7) * per + (l >> 3);
    tx = swz % gx;
    ty = swz / gx;
}

#define GLOBAL_TO_LDS16(gp, lp)                                                           \
    __builtin_amdgcn_global_load_lds((const __attribute__((address_space(1))) void*)(gp), \
                                     (__attribute__((address_space(3))) void*)(lp), 16, 0, 0)

// ---------- bf16 GEMM: projections (counted-vmcnt dbuf pipeline) ----------
__global__ __launch_bounds__(256, 2) void gemm_proj(
    const u16* __restrict__ Ac, const u16* __restrict__ Aq, int lda,
    const u16* __restrict__ Bp, long sBz, int ldb,
    u8* __restrict__ C8, long sCz, int ldc, int K,
    const float* __restrict__ bc, const float* __restrict__ bq) {
    __shared__ __align__(16) u16 As[2][128 * 64];
    __shared__ __align__(16) u16 Bs[2][128 * 64];

    const int tid  = threadIdx.x;
    const int lane = tid & 63;
    const int wave = tid >> 6;
    const int z    = blockIdx.z;

    const u16* a = z ? Aq : Ac;
    const u16* b = Bp + (long)z * sBz;
    const float* bias = z ? bq : bc;

    int tx, ty;
    xcd_tile(tx, ty);
    const int tileM = ty * 128;
    const int tileN = tx * 128;

    const int wm  = wave >> 1;
    const int wn  = wave & 1;
    const int r16 = lane & 15;
    const int kg  = lane >> 4;

    const int srow = lane >> 3;
    const int sgc  = ((lane & 7) ^ (lane >> 3)) * 8;
    const int swb  = r16 & 7;

    auto stage = [&](int buf, int t) {
        const int k0 = t * 64;
#pragma unroll
        for (int p = 0; p < 4; p++) {
            const int rbase = p * 32 + wave * 8;
            GLOBAL_TO_LDS16(a + (long)(tileM + rbase + srow) * lda + k0 + sgc, &As[buf][rbase * 64]);
            GLOBAL_TO_LDS16(b + (long)(tileN + rbase + srow) * ldb + k0 + sgc, &Bs[buf][rbase * 64]);
        }
    };

    f32x4 acc[4][4] = {};

    const int nt = K / 64;
    stage(0, 0);
    stage(1, 1);

    for (int t = 0; t < nt; t++) {
        const int cur = t & 1;
        if (t + 1 < nt) asm volatile("s_waitcnt vmcnt(8)" ::: "memory");
        else            asm volatile("s_waitcnt vmcnt(0)" ::: "memory");
        __builtin_amdgcn_s_barrier();
        asm volatile("" ::: "memory");

        bf16x8 af[2][4], bfr[2][4];
#pragma unroll
        for (int h = 0; h < 2; h++) {
#pragma unroll
            for (int i = 0; i < 4; i++) {
                const int Ra = wm * 64 + i * 16 + r16;
                af[h][i]  = *(const bf16x8*)&As[cur][Ra * 64 + (((h * 4 + kg) ^ swb)) * 8];
                const int Rb = wn * 64 + i * 16 + r16;
                bfr[h][i] = *(const bf16x8*)&Bs[cur][Rb * 64 + (((h * 4 + kg) ^ swb)) * 8];
            }
        }
#pragma unroll
        for (int h = 0; h < 2; h++)
#pragma unroll
            for (int i = 0; i < 4; i++)
#pragma unroll
                for (int j = 0; j < 4; j++)
                    acc[i][j] = __builtin_amdgcn_mfma_f32_16x16x32_bf16(
                        af[h][i], bfr[h][j], acc[i][j], 0, 0, 0);

        asm volatile("" ::: "memory");
        __builtin_amdgcn_s_barrier();
        if (t + 2 < nt) stage(cur, t + 2);
    }

#pragma unroll
    for (int i = 0; i < 4; i++)
#pragma unroll
        for (int j = 0; j < 4; j++) {
            int col = tileN + wn * 64 + j * 16 + r16;
            float bv = bias[col];
#pragma unroll
            for (int v = 0; v < 4; v++) {
                int row = tileM + wm * 64 + i * 16 + kg * 4 + v;
                C8[(long)z * sCz + (long)row * ldc + col] = f2fp8(acc[i][j][v] + bv);
            }
        }
}

// ---------- fp8 GEMM: gate / sim / PV (single-buf, MX-scaled MFMA) ----------
// MODE 1: C16 = sigmoid(acc + bias[col])            (gate; A0->A1 @ kSplit)
// MODE 2: C8  = exp(acc*scale); atomicAdd row sums  (sim; LDS-coalesced store)
// MODE 4: C32 = cls + g16 * (acc / lsum[row])       (PV + merge)
template <int MODE>
__global__ __launch_bounds__(256, 2) void gemm8(
    const u8* __restrict__ A0, const u8* __restrict__ A1, long sAz, int lda, int kSplit,
    const u8* __restrict__ Bp, long sBz, int ldb,
    void* __restrict__ Cp, long cOff, long sCz, int ldc, int K,
    const float* __restrict__ bias, const float* __restrict__ temp,
    const float* __restrict__ cls, const u16* __restrict__ g16,
    float* __restrict__ lsum, long lSz) {
    __shared__ __align__(16) u8 As[128 * 128];
    __shared__ __align__(16) u8 Bs[128 * 128];

    const int tid  = threadIdx.x;
    const int lane = tid & 63;
    const int wave = tid >> 6;
    const int z    = blockIdx.z;

    const u8* a = A0 + (long)z * sAz;
    const u8* b = Bp + (long)z * sBz;

    int tx, ty;
    xcd_tile(tx, ty);
    const int tileM = ty * 128;
    const int tileN = tx * 128;

    const int wm  = wave >> 1;
    const int wn  = wave & 1;
    const int r16 = lane & 15;
    const int kg  = lane >> 4;

    const int srow = lane >> 3;
    const int sgc  = ((lane & 7) ^ (lane >> 3)) * 16;

    f32x4 acc[4][4] = {};

    for (int k0 = 0; k0 < K; k0 += 128) {
        const u8* Ap = a;
        int kA = k0;
        if (MODE == 1 && k0 >= kSplit) { Ap = A1; kA = k0 - kSplit; }

#pragma unroll
        for (int p = 0; p < 4; p++) {
            const int rbase = p * 32 + wave * 8;
            GLOBAL_TO_LDS16(Ap + (long)(tileM + rbase + srow) * lda + kA + sgc, &As[rbase * 128]);
            GLOBAL_TO_LDS16(b + (long)(tileN + rbase + srow) * ldb + k0 + sgc, &Bs[rbase * 128]);
        }
        __syncthreads();

        // lane covers k-bytes [kg*32, kg*32+32) of its rows; frags built in place
        i32x8 af[4];
#pragma unroll
        for (int i = 0; i < 4; i++) {
            const int Ra = wm * 64 + i * 16 + r16;
            const u8* base = &As[Ra * 128];
            *(i32x4*)&af[i]       = *(const i32x4*)&base[(((2 * kg)     ^ (Ra & 7))) * 16];
            *((i32x4*)&af[i] + 1) = *(const i32x4*)&base[(((2 * kg + 1) ^ (Ra & 7))) * 16];
        }
#pragma unroll
        for (int j = 0; j < 4; j++) {
            const int Rb = wn * 64 + j * 16 + r16;
            const u8* base = &Bs[Rb * 128];
            i32x8 bfr;
            *(i32x4*)&bfr       = *(const i32x4*)&base[(((2 * kg)     ^ (Rb & 7))) * 16];
            *((i32x4*)&bfr + 1) = *(const i32x4*)&base[(((2 * kg + 1) ^ (Rb & 7))) * 16];
#pragma unroll
            for (int i = 0; i < 4; i++)
                acc[i][j] = __builtin_amdgcn_mfma_scale_f32_16x16x128_f8f6f4(
                    af[i], bfr, acc[i][j], 0, 0, 0, 127, 0, 127);
        }
        __syncthreads();
    }

    u16*   C16 = (u16*)Cp;
    u8*    C8  = (u8*)Cp;
    float* C32 = (float*)Cp;

    if constexpr (MODE == 2) {
        const float scale = 1.0f / (32.0f * temp[0]);  // 1/(sqrt(1024)*temperature)
        u8* Cs = As;  // reuse: 128x128 staging (LDS free after last __syncthreads)
#pragma unroll
        for (int i = 0; i < 4; i++) {
            float rs[4] = {0.f, 0.f, 0.f, 0.f};
#pragma unroll
            for (int j = 0; j < 4; j++) {
                const int lcol = wn * 64 + j * 16 + r16;
#pragma unroll
                for (int v = 0; v < 4; v++) {
                    const int lrow = wm * 64 + i * 16 + kg * 4 + v;
                    float e = __expf(acc[i][j][v] * scale);
                    // XOR col bits 4-5 with row bits 2-3 to spread kg-groups over banks
                    Cs[lrow * 128 + (lcol ^ ((lrow & 12) << 2))] = f2fp8(e);
                    rs[v] += e;
                }
            }
#pragma unroll
            for (int v = 0; v < 4; v++) {
                float s = rs[v];
#pragma unroll
                for (int off = 1; off < 16; off <<= 1) s += __shfl_xor(s, off, 64);
                if (r16 == 0) {
                    int row = tileM + wm * 64 + i * 16 + kg * 4 + v;
                    atomicAdd(&lsum[(long)z * lSz + row], s);
                }
            }
        }
        __syncthreads();
        // coalesced store: thread -> (row = tid>>1, 64B half = (tid&1)*64)
        const int r  = tid >> 1;
        const int ch = (tid & 1) * 64;
        const int rk = (r >> 2) & 3;  // row bits 2-3 (XOR key)
        i32x4 w[4];
#pragma unroll
        for (int m = 0; m < 4; m++)
            w[m] = *(const i32x4*)&Cs[r * 128 + ch + ((m ^ rk) << 4)];
        long base = cOff + (long)z * sCz + (long)(tileM + r) * ldc + tileN + ch;
#pragma unroll
        for (int m = 0; m < 4; m++)
            *(i32x4*)&C8[base + m * 16] = w[m];
    } else {
#pragma unroll
        for (int i = 0; i < 4; i++) {
#pragma unroll
            for (int j = 0; j < 4; j++) {
                int col = tileN + wn * 64 + j * 16 + r16;
                float bv = (MODE == 1) ? bias[col] : 0.0f;
#pragma unroll
                for (int v = 0; v < 4; v++) {
                    int row = tileM + wm * 64 + i * 16 + kg * 4 + v;
                    long idx = cOff + (long)z * sCz + (long)row * ldc + col;
                    float val = acc[i][j][v];
                    if (MODE == 1) {
                        C16[idx] = f2bf(1.0f / (1.0f + __expf(-(val + bv))));
                    } else {  // MODE 4
                        float inv = 1.0f / lsum[(long)z * lSz + row];
                        C32[idx] = cls[idx] + bf2f(g16[idx]) * (val * inv);
                    }
                }
            }
        }
    }
}

// Fused prep: cls->bf16, qnt->bf16, Wc->bf16, Wq->bf16, Wg->fp8, l->0.
__global__ __launch_bounds__(256) void prep(
    const f32x4* __restrict__ cls, const f32x4* __restrict__ qnt,
    const f32x4* __restrict__ Wc, const f32x4* __restrict__ Wq, const f32x4* __restrict__ Wg,
    ushort4* __restrict__ clsB, ushort4* __restrict__ qntB,
    ushort4* __restrict__ WcB, ushort4* __restrict__ WqB, unsigned int* __restrict__ Wg8,
    f32x4* __restrict__ l, long nM, long nW, long nG, long nL) {
    long i = (long)blockIdx.x * 256 + threadIdx.x;
    long stride = (long)gridDim.x * 256;
    long total = 2 * nM + 2 * nW + nG + nL;
    for (; i < total; i += stride) {
        if (i < 2 * nM) {
            long j = (i < nM) ? i : i - nM;
            f32x4 v = (i < nM) ? cls[j] : qnt[j];
            ushort4 o;
            o.x = f2bf(v.x); o.y = f2bf(v.y); o.z = f2bf(v.z); o.w = f2bf(v.w);
            if (i < nM) clsB[j] = o; else qntB[j] = o;
        } else if (i < 2 * nM + 2 * nW) {
            long j = i - 2 * nM;
            long k = (j < nW) ? j : j - nW;
            f32x4 v = (j < nW) ? Wc[k] : Wq[k];
            ushort4 o;
            o.x = f2bf(v.x); o.y = f2bf(v.y); o.z = f2bf(v.z); o.w = f2bf(v.w);
            if (j < nW) WcB[k] = o; else WqB[k] = o;
        } else if (i < 2 * nM + 2 * nW + nG) {
            long j = i - 2 * nM - 2 * nW;
            f32x4 v = Wg[j];
            int w = __builtin_amdgcn_cvt_pk_fp8_f32(v.x, v.y, 0, false);
            w = __builtin_amdgcn_cvt_pk_fp8_f32(v.z, v.w, w, true);
            Wg8[j] = (unsigned int)w;
        } else {
            l[i - 2 * nM - 2 * nW - nG] = (f32x4){0.f, 0.f, 0.f, 0.f};
        }
    }
}

// qT8[b][d][t] = fp8(Q[b][t][d]), Q bf16. Vectorized: short8 loads, 16B stores.
__global__ __launch_bounds__(256) void transpose_fp8(const u16* __restrict__ Q,
                                                     u8* __restrict__ QT, int S, int D) {
    __shared__ __align__(16) u8 tile[64][80];  // 80B stride: 16B-aligned rows
    int bz = blockIdx.z;
    const u16* q = Q + (long)bz * S * D;
    u8* qt = QT + (long)bz * S * D;
    int t0 = blockIdx.x * 64;
    int d0 = blockIdx.y * 64;
    {
        // load: thread -> (t-row = tid>>2, 16 d-cols at (tid&3)*16)
        const int r  = threadIdx.x >> 2;
        const int dc = (threadIdx.x & 3) * 16;
        const u16* src = q + (long)(t0 + r) * D + d0 + dc;
        short8 a = *(const short8*)src;
        short8 bqv = *(const short8*)(src + 8);
        unsigned int pk[4];
#pragma unroll
        for (int m = 0; m < 2; m++) {
            int w = __builtin_amdgcn_cvt_pk_fp8_f32(
                bf2f((u16)a[4 * m + 0]), bf2f((u16)a[4 * m + 1]), 0, false);
            w = __builtin_amdgcn_cvt_pk_fp8_f32(
                bf2f((u16)a[4 * m + 2]), bf2f((u16)a[4 * m + 3]), w, true);
            pk[m] = (unsigned int)w;
        }
#pragma unroll
        for (int m = 0; m < 2; m++) {
            int w = __builtin_amdgcn_cvt_pk_fp8_f32(
                bf2f((u16)bqv[4 * m + 0]), bf2f((u16)bqv[4 * m + 1]), 0, false);
            w = __builtin_amdgcn_cvt_pk_fp8_f32(
                bf2f((u16)bqv[4 * m + 2]), bf2f((u16)bqv[4 * m + 3]), w, true);
            pk[2 + m] = (unsigned int)w;
        }
        *(i32x4*)&tile[r][dc] = *(i32x4*)pk;
    }
    __syncthreads();
    {
        // store: thread -> (d-row = tid>>2, 16 t-cols at (tid&3)*16), 16B write
        const int dl = threadIdx.x >> 2;
        const int tc = (threadIdx.x & 3) * 16;
        unsigned int w[4];
#pragma unroll
        for (int m = 0; m < 4; m++) {
            unsigned int x = 0;
#pragma unroll
            for (int k = 0; k < 4; k++)
                x |= (unsigned int)tile[tc + m * 4 + k][dl] << (8 * k);
            w[m] = x;
        }
        *(i32x4*)&qt[(long)(d0 + dl) * S + t0 + tc] = *(i32x4*)w;
    }
}

extern "C" void kernel_launch(void* const* d_in, const int* in_sizes, int n_in,
                              void* d_out, int out_size, void* d_ws, size_t ws_size,
                              hipStream_t stream) {
    (void)in_sizes; (void)n_in; (void)out_size;

    const float* classical = (const float*)d_in[0];
    const float* quantum   = (const float*)d_in[1];
    const float* Wc        = (const float*)d_in[2];
    const float* bc        = (const float*)d_in[3];
    const float* Wq        = (const float*)d_in[4];
    const float* bq        = (const float*)d_in[5];
    const float* Wg        = (const float*)d_in[6];
    const float* bg        = (const float*)d_in[7];
    const float* temp      = (const float*)d_in[8];
    float* out = (float*)d_out;

    const int B = 4, S = 2048, D = 1024;
    const long MD = (long)B * S * D;  // 8388608

    float* l    = (float*)d_ws;                    // B*S f32
    u16* Wc_b   = (u16*)(l + (long)B * S);         // D*D u16
    u16* Wq_b   = Wc_b + (long)D * D;              // D*D u16
    u8*  Wg8    = (u8*)(Wq_b + (long)D * D);       // D*2D bytes
    u16* cls_b  = (u16*)(Wg8 + (long)D * 2 * D);   // MD u16 (g overlay after proj)
    u16* qnt_b  = cls_b + MD;                      // MD u16
    u8*  cp8    = (u8*)(qnt_b + MD);               // MD bytes
    u8*  qp8    = cp8 + MD;                        // MD bytes
    u8*  qT8    = qp8 + MD;                        // MD bytes
    u8*  P8     = qT8 + MD;                        // B*CH*S bytes
    u16* g      = cls_b;                           // overlay: cls_b dead after proj

    const size_t fixed_bytes = (size_t)B * S * 4 + 2 * (size_t)D * D * 2 +
        (size_t)D * 2 * D + 2 * (size_t)MD * 2 + 3 * (size_t)MD;
    int CH = 128;
    for (int c = 2048; c >= 128; c >>= 1) {
        if (ws_size >= fixed_bytes + (size_t)B * c * S) { CH = c; break; }
    }

    dim3 blk(256);

    prep<<<2048, blk, 0, stream>>>(
        (const f32x4*)classical, (const f32x4*)quantum,
        (const f32x4*)Wc, (const f32x4*)Wq, (const f32x4*)Wg,
        (ushort4*)cls_b, (ushort4*)qnt_b,
        (ushort4*)Wc_b, (ushort4*)Wq_b, (unsigned int*)Wg8,
        (f32x4*)l, MD / 4, (long)D * D / 4, (long)D * 2 * D / 4, (long)B * S / 4);

    // fused projections (z=2): {cp8,qp8} = fp8({cls,qnt}@{Wc,Wq}^T + {bc,bq})
    gemm_proj<<<dim3(D / 128, (B * S) / 128, 2), blk, 0, stream>>>(
        cls_b, qnt_b, D, Wc_b, (long)D * D, D, cp8, MD, D, D, bc, bq);

    // gate: g = sigmoid([cp8|qp8]@Wg8^T + bg)  (bf16, overlays cls_b)
    gemm8<1><<<dim3(D / 128, (B * S) / 128, 1), blk, 0, stream>>>(
        cp8, qp8, 0, D, D, Wg8, 0, 2 * D, g, 0, 0, D, 2 * D,
        bg, nullptr, nullptr, nullptr, nullptr, 0);

    // quantum^T (fp8) per batch
    transpose_fp8<<<dim3(S / 64, D / 64, B), blk, 0, stream>>>(qnt_b, qT8, S, D);

    // attention, z-batched, CH-row chunks:
    //   P8 = fp8(exp(cp8@qp8^T/(32 t))), l += row sums; out = cls + g*(P8@qT8^T)/l
    for (int m0 = 0; m0 < S; m0 += CH) {
        gemm8<2><<<dim3(S / 128, CH / 128, B), blk, 0, stream>>>(
            cp8 + (long)m0 * D, nullptr, (long)S * D, D, 1 << 30,
            qp8, (long)S * D, D, P8, 0, (long)CH * S, S, D,
            nullptr, temp, nullptr, nullptr, l + m0, S);
        gemm8<4><<<dim3(D / 128, CH / 128, B), blk, 0, stream>>>(
            P8, nullptr, (long)CH * S, S, 1 << 30, qT8, (long)D * S, S,
            out, (long)m0 * D, (long)S * D, D, S,
            nullptr, nullptr, classical, g, l + m0, S);
    }
}

// Round 8
// 247.685 us; speedup vs baseline: 1.0782x; 1.0782x over previous
//
#include <hip/hip_runtime.h>

// QuantumClassicalInterface on MI355X (gfx950). Round 16.
// f32 I/O. 4 dispatches: prepT (prep + qT transpose from f32), gemm_proj
// (bf16 MFMA 128^2 BK=64, counted-vmcnt dbuf), gateSim (gate+sim fused via
// block-range split, MX-scaled fp8 MFMA 128^2 single-buf), gemm8<4> (PV+merge).
// R16: dispatch count 6 -> 4. Inner loops unchanged from R15 (all proven).
// ~65us of the R7 budget was inter-dispatch overhead (~8-10us/launch);
// transpose is independent of prep (reads f32 quantum directly, R11-proven),
// gate and sim are independent given proj outputs -> fuse both pairs.
// Softmax fused (exp + atomic row sums; logits bounded so no max-sub needed).
// PV epilogue does final merge: out = classical + g * (P@quantum)/l.

typedef unsigned short u16;
typedef unsigned char u8;
typedef __bf16 bf16x8 __attribute__((ext_vector_type(8)));
typedef float f32x4 __attribute__((ext_vector_type(4)));
typedef int i32x4 __attribute__((ext_vector_type(4)));
typedef int i32x8 __attribute__((ext_vector_type(8)));
typedef short short8 __attribute__((ext_vector_type(8)));

__device__ __forceinline__ u16 f2bf(float f) {
    unsigned int x;
    __builtin_memcpy(&x, &f, 4);
    unsigned int r = x + 0x7FFFu + ((x >> 16) & 1u);
    return (u16)(r >> 16);
}
__device__ __forceinline__ float bf2f(u16 u) {
    unsigned int x = ((unsigned int)u) << 16;
    float f;
    __builtin_memcpy(&f, &x, 4);
    return f;
}
__device__ __forceinline__ u8 f2fp8(float f) {
    int p = __builtin_amdgcn_cvt_pk_fp8_f32(f, f, 0, false);
    return (u8)(p & 0xFF);
}

// XCD-aware bijective swizzle of the (x,y) tile space (nwg % 8 == 0 here).
__device__ __forceinline__ void xcd_tile(int& tx, int& ty) {
    const int gx = gridDim.x;
    const int nwg = gx * gridDim.y;
    const int l = blockIdx.x + gx * blockIdx.y;
    const int per = nwg >> 3;
    const int swz = (l & 7) * per + (l >> 3);
    tx = swz % gx;
    ty = swz / gx;
}

#define GLOBAL_TO_LDS16(gp, lp)                                                           \
    __builtin_amdgcn_global_load_lds((const __attribute__((address_space(1))) void*)(gp), \
                                     (__attribute__((address_space(3))) void*)(lp), 16, 0, 0)

// ---------- bf16 GEMM: projections (counted-vmcnt dbuf pipeline) ----------
__global__ __launch_bounds__(256, 2) void gemm_proj(
    const u16* __restrict__ Ac, const u16* __restrict__ Aq, int lda,
    const u16* __restrict__ Bp, long sBz, int ldb,
    u8* __restrict__ C8, long sCz, int ldc, int K,
    const float* __restrict__ bc, const float* __restrict__ bq) {
    __shared__ __align__(16) u16 As[2][128 * 64];
    __shared__ __align__(16) u16 Bs[2][128 * 64];

    const int tid  = threadIdx.x;
    const int lane = tid & 63;
    const int wave = tid >> 6;
    const int z    = blockIdx.z;

    const u16* a = z ? Aq : Ac;
    const u16* b = Bp + (long)z * sBz;
    const float* bias = z ? bq : bc;

    int tx, ty;
    xcd_tile(tx, ty);
    const int tileM = ty * 128;
    const int tileN = tx * 128;

    const int wm  = wave >> 1;
    const int wn  = wave & 1;
    const int r16 = lane & 15;
    const int kg  = lane >> 4;

    const int srow = lane >> 3;
    const int sgc  = ((lane & 7) ^ (lane >> 3)) * 8;
    const int swb  = r16 & 7;

    auto stage = [&](int buf, int t) {
        const int k0 = t * 64;
#pragma unroll
        for (int p = 0; p < 4; p++) {
            const int rbase = p * 32 + wave * 8;
            GLOBAL_TO_LDS16(a + (long)(tileM + rbase + srow) * lda + k0 + sgc, &As[buf][rbase * 64]);
            GLOBAL_TO_LDS16(b + (long)(tileN + rbase + srow) * ldb + k0 + sgc, &Bs[buf][rbase * 64]);
        }
    };

    f32x4 acc[4][4] = {};

    const int nt = K / 64;
    stage(0, 0);
    stage(1, 1);

    for (int t = 0; t < nt; t++) {
        const int cur = t & 1;
        if (t + 1 < nt) asm volatile("s_waitcnt vmcnt(8)" ::: "memory");
        else            asm volatile("s_waitcnt vmcnt(0)" ::: "memory");
        __builtin_amdgcn_s_barrier();
        asm volatile("" ::: "memory");

        bf16x8 af[2][4], bfr[2][4];
#pragma unroll
        for (int h = 0; h < 2; h++) {
#pragma unroll
            for (int i = 0; i < 4; i++) {
                const int Ra = wm * 64 + i * 16 + r16;
                af[h][i]  = *(const bf16x8*)&As[cur][Ra * 64 + (((h * 4 + kg) ^ swb)) * 8];
                const int Rb = wn * 64 + i * 16 + r16;
                bfr[h][i] = *(const bf16x8*)&Bs[cur][Rb * 64 + (((h * 4 + kg) ^ swb)) * 8];
            }
        }
#pragma unroll
        for (int h = 0; h < 2; h++)
#pragma unroll
            for (int i = 0; i < 4; i++)
#pragma unroll
                for (int j = 0; j < 4; j++)
                    acc[i][j] = __builtin_amdgcn_mfma_f32_16x16x32_bf16(
                        af[h][i], bfr[h][j], acc[i][j], 0, 0, 0);

        asm volatile("" ::: "memory");
        __builtin_amdgcn_s_barrier();
        if (t + 2 < nt) stage(cur, t + 2);
    }

#pragma unroll
    for (int i = 0; i < 4; i++)
#pragma unroll
        for (int j = 0; j < 4; j++) {
            int col = tileN + wn * 64 + j * 16 + r16;
            float bv = bias[col];
#pragma unroll
            for (int v = 0; v < 4; v++) {
                int row = tileM + wm * 64 + i * 16 + kg * 4 + v;
                C8[(long)z * sCz + (long)row * ldc + col] = f2fp8(acc[i][j][v] + bv);
            }
        }
}

// ---------- fp8 GEMM body: gate / sim / PV (single-buf, MX-scaled MFMA) ----------
// MODE 1: C16 = sigmoid(acc + bias[col])            (gate; A0->A1 @ kSplit)
// MODE 2: C8  = exp(acc*scale); atomicAdd row sums  (sim; LDS-coalesced store)
// MODE 4: C32 = cls + g16 * (acc / lsum[row])       (PV + merge)
template <int MODE>
__device__ __forceinline__ void gemm8_body(
    int tileM, int tileN, int z, int tid,
    const u8* __restrict__ A0, const u8* __restrict__ A1, long sAz, int lda, int kSplit,
    const u8* __restrict__ Bp, long sBz, int ldb,
    void* __restrict__ Cp, long cOff, long sCz, int ldc, int K,
    const float* __restrict__ bias, const float* __restrict__ temp,
    const float* __restrict__ cls, const u16* __restrict__ g16,
    float* __restrict__ lsum, long lSz,
    u8* As, u8* Bs) {
    const int lane = tid & 63;
    const int wave = tid >> 6;

    const u8* a = A0 + (long)z * sAz;
    const u8* b = Bp + (long)z * sBz;

    const int wm  = wave >> 1;
    const int wn  = wave & 1;
    const int r16 = lane & 15;
    const int kg  = lane >> 4;

    const int srow = lane >> 3;
    const int sgc  = ((lane & 7) ^ (lane >> 3)) * 16;

    f32x4 acc[4][4] = {};

    for (int k0 = 0; k0 < K; k0 += 128) {
        const u8* Ap = a;
        int kA = k0;
        if (MODE == 1 && k0 >= kSplit) { Ap = A1; kA = k0 - kSplit; }

#pragma unroll
        for (int p = 0; p < 4; p++) {
            const int rbase = p * 32 + wave * 8;
            GLOBAL_TO_LDS16(Ap + (long)(tileM + rbase + srow) * lda + kA + sgc, &As[rbase * 128]);
            GLOBAL_TO_LDS16(b + (long)(tileN + rbase + srow) * ldb + k0 + sgc, &Bs[rbase * 128]);
        }
        __syncthreads();

        // lane covers k-bytes [kg*32, kg*32+32) of its rows; frags built in place
        i32x8 af[4];
#pragma unroll
        for (int i = 0; i < 4; i++) {
            const int Ra = wm * 64 + i * 16 + r16;
            const u8* base = &As[Ra * 128];
            *(i32x4*)&af[i]       = *(const i32x4*)&base[(((2 * kg)     ^ (Ra & 7))) * 16];
            *((i32x4*)&af[i] + 1) = *(const i32x4*)&base[(((2 * kg + 1) ^ (Ra & 7))) * 16];
        }
#pragma unroll
        for (int j = 0; j < 4; j++) {
            const int Rb = wn * 64 + j * 16 + r16;
            const u8* base = &Bs[Rb * 128];
            i32x8 bfr;
            *(i32x4*)&bfr       = *(const i32x4*)&base[(((2 * kg)     ^ (Rb & 7))) * 16];
            *((i32x4*)&bfr + 1) = *(const i32x4*)&base[(((2 * kg + 1) ^ (Rb & 7))) * 16];
#pragma unroll
            for (int i = 0; i < 4; i++)
                acc[i][j] = __builtin_amdgcn_mfma_scale_f32_16x16x128_f8f6f4(
                    af[i], bfr, acc[i][j], 0, 0, 0, 127, 0, 127);
        }
        __syncthreads();
    }

    u16*   C16 = (u16*)Cp;
    u8*    C8  = (u8*)Cp;
    float* C32 = (float*)Cp;

    if constexpr (MODE == 2) {
        const float scale = 1.0f / (32.0f * temp[0]);  // 1/(sqrt(1024)*temperature)
        u8* Cs = As;  // reuse: 128x128 staging (LDS free after last __syncthreads)
#pragma unroll
        for (int i = 0; i < 4; i++) {
            float rs[4] = {0.f, 0.f, 0.f, 0.f};
#pragma unroll
            for (int j = 0; j < 4; j++) {
                const int lcol = wn * 64 + j * 16 + r16;
#pragma unroll
                for (int v = 0; v < 4; v++) {
                    const int lrow = wm * 64 + i * 16 + kg * 4 + v;
                    float e = __expf(acc[i][j][v] * scale);
                    Cs[lrow * 128 + (lcol ^ ((lrow & 12) << 2))] = f2fp8(e);
                    rs[v] += e;
                }
            }
#pragma unroll
            for (int v = 0; v < 4; v++) {
                float s = rs[v];
#pragma unroll
                for (int off = 1; off < 16; off <<= 1) s += __shfl_xor(s, off, 64);
                if (r16 == 0) {
                    int row = tileM + wm * 64 + i * 16 + kg * 4 + v;
                    atomicAdd(&lsum[(long)z * lSz + row], s);
                }
            }
        }
        __syncthreads();
        const int r  = tid >> 1;
        const int ch = (tid & 1) * 64;
        const int rk = (r >> 2) & 3;
        i32x4 w[4];
#pragma unroll
        for (int m = 0; m < 4; m++)
            w[m] = *(const i32x4*)&Cs[r * 128 + ch + ((m ^ rk) << 4)];
        long base = cOff + (long)z * sCz + (long)(tileM + r) * ldc + tileN + ch;
#pragma unroll
        for (int m = 0; m < 4; m++)
            *(i32x4*)&C8[base + m * 16] = w[m];
    } else {
#pragma unroll
        for (int i = 0; i < 4; i++) {
#pragma unroll
            for (int j = 0; j < 4; j++) {
                int col = tileN + wn * 64 + j * 16 + r16;
                float bv = (MODE == 1) ? bias[col] : 0.0f;
#pragma unroll
                for (int v = 0; v < 4; v++) {
                    int row = tileM + wm * 64 + i * 16 + kg * 4 + v;
                    long idx = cOff + (long)z * sCz + (long)row * ldc + col;
                    float val = acc[i][j][v];
                    if (MODE == 1) {
                        C16[idx] = f2bf(1.0f / (1.0f + __expf(-(val + bv))));
                    } else {  // MODE 4
                        float inv = 1.0f / lsum[(long)z * lSz + row];
                        C32[idx] = cls[idx] + bf2f(g16[idx]) * (val * inv);
                    }
                }
            }
        }
    }
}

// Standalone wrapper (used for PV always; sim/PV extra chunks if CH < S)
template <int MODE>
__global__ __launch_bounds__(256, 2) void gemm8(
    const u8* __restrict__ A0, const u8* __restrict__ A1, long sAz, int lda, int kSplit,
    const u8* __restrict__ Bp, long sBz, int ldb,
    void* __restrict__ Cp, long cOff, long sCz, int ldc, int K,
    const float* __restrict__ bias, const float* __restrict__ temp,
    const float* __restrict__ cls, const u16* __restrict__ g16,
    float* __restrict__ lsum, long lSz) {
    __shared__ __align__(16) u8 As[128 * 128];
    __shared__ __align__(16) u8 Bs[128 * 128];
    int tx, ty;
    xcd_tile(tx, ty);
    gemm8_body<MODE>(ty * 128, tx * 128, blockIdx.z, threadIdx.x,
                     A0, A1, sAz, lda, kSplit, Bp, sBz, ldb,
                     Cp, cOff, sCz, ldc, K, bias, temp, cls, g16, lsum, lSz, As, Bs);
}

// Fused gate + sim: blocks [0,512) = gate tiles, [512, 512+4*nwgSim) = sim tiles.
// Sub-range bases are multiples of 8, so bid%8 (XCD) parity matches the
// standalone launches; per-range bijective swizzles preserved.
__global__ __launch_bounds__(256, 2) void gateSim(
    const u8* __restrict__ cp8, const u8* __restrict__ qp8,
    const u8* __restrict__ Wg8, u16* __restrict__ g, const float* __restrict__ bg,
    u8* __restrict__ P8, long sP, const float* __restrict__ temp,
    float* __restrict__ lsum, long lSz,
    long sBD, int D, int S, int nwgSim) {
    __shared__ __align__(16) u8 As[128 * 128];
    __shared__ __align__(16) u8 Bs[128 * 128];
    const int bid = blockIdx.x;
    if (bid < 512) {
        // gate: virtual grid (8, 64)
        const int swz = (bid & 7) * 64 + (bid >> 3);
        const int tx = swz & 7, ty = swz >> 3;
        gemm8_body<1>(ty * 128, tx * 128, 0, threadIdx.x,
                      cp8, qp8, 0, D, D, Wg8, 0, 2 * D,
                      g, 0, 0, D, 2 * D,
                      bg, nullptr, nullptr, nullptr, nullptr, 0, As, Bs);
    } else {
        // sim: virtual grid (16, nwgSim/16, 4)
        const int sb  = bid - 512;
        const int z   = sb / nwgSim;
        const int lid = sb - z * nwgSim;
        const int per = nwgSim >> 3;
        const int swz = (lid & 7) * per + (lid >> 3);
        const int tx = swz & 15, ty = swz >> 4;
        gemm8_body<2>(ty * 128, tx * 128, z, threadIdx.x,
                      cp8, nullptr, sBD, D, 1 << 30, qp8, sBD, D,
                      P8, 0, sP, S, D,
                      nullptr, temp, nullptr, nullptr, lsum, lSz, As, Bs);
    }
}

// Fused prep + qT transpose. Blocks [0,2048): grid-stride converts
// (cls/qnt -> bf16, Wc/Wq -> bf16, Wg -> fp8, l -> 0). Blocks [2048, 4096):
// qT8[b][d][t] = fp8(quantum_f32[b][t][d]) — independent of the prep half.
__global__ __launch_bounds__(256) void prepT(
    const f32x4* __restrict__ cls, const f32x4* __restrict__ qnt,
    const f32x4* __restrict__ Wc, const f32x4* __restrict__ Wq, const f32x4* __restrict__ Wg,
    ushort4* __restrict__ clsB, ushort4* __restrict__ qntB,
    ushort4* __restrict__ WcB, ushort4* __restrict__ WqB, unsigned int* __restrict__ Wg8,
    f32x4* __restrict__ l, long nM, long nW, long nG, long nL,
    const float* __restrict__ Qf, u8* __restrict__ QT, int S, int D) {
    __shared__ __align__(16) u8 tile[64][80];
    const int bid = blockIdx.x;
    if (bid < 2048) {
        long i = (long)bid * 256 + threadIdx.x;
        const long stride = 2048L * 256;
        const long total = 2 * nM + 2 * nW + nG + nL;
        for (; i < total; i += stride) {
            if (i < 2 * nM) {
                long j = (i < nM) ? i : i - nM;
                f32x4 v = (i < nM) ? cls[j] : qnt[j];
                ushort4 o;
                o.x = f2bf(v.x); o.y = f2bf(v.y); o.z = f2bf(v.z); o.w = f2bf(v.w);
                if (i < nM) clsB[j] = o; else qntB[j] = o;
            } else if (i < 2 * nM + 2 * nW) {
                long j = i - 2 * nM;
                long k = (j < nW) ? j : j - nW;
                f32x4 v = (j < nW) ? Wc[k] : Wq[k];
                ushort4 o;
                o.x = f2bf(v.x); o.y = f2bf(v.y); o.z = f2bf(v.z); o.w = f2bf(v.w);
                if (j < nW) WcB[k] = o; else WqB[k] = o;
            } else if (i < 2 * nM + 2 * nW + nG) {
                long j = i - 2 * nM - 2 * nW;
                f32x4 v = Wg[j];
                int w = __builtin_amdgcn_cvt_pk_fp8_f32(v.x, v.y, 0, false);
                w = __builtin_amdgcn_cvt_pk_fp8_f32(v.z, v.w, w, true);
                Wg8[j] = (unsigned int)w;
            } else {
                l[i - 2 * nM - 2 * nW - nG] = (f32x4){0.f, 0.f, 0.f, 0.f};
            }
        }
    } else {
        const int tb = bid - 2048;            // grid (S/64=32, D/64=16, B=4)
        const int bx = tb & 31;
        const int by = (tb >> 5) & 15;
        const int bz = tb >> 9;
        const float* q = Qf + (long)bz * S * D;
        u8* qt = QT + (long)bz * S * D;
        const int t0 = bx * 64, d0 = by * 64;
        {
            const int r  = threadIdx.x >> 2;
            const int dc = (threadIdx.x & 3) * 16;
            const float* src = q + (long)(t0 + r) * D + d0 + dc;
            unsigned int pk[4];
#pragma unroll
            for (int m = 0; m < 4; m++) {
                f32x4 v = *(const f32x4*)(src + 4 * m);
                int w = __builtin_amdgcn_cvt_pk_fp8_f32(v.x, v.y, 0, false);
                w = __builtin_amdgcn_cvt_pk_fp8_f32(v.z, v.w, w, true);
                pk[m] = (unsigned int)w;
            }
            *(i32x4*)&tile[r][dc] = *(i32x4*)pk;
        }
        __syncthreads();
        {
            const int dl = threadIdx.x >> 2;
            const int tc = (threadIdx.x & 3) * 16;
            unsigned int w[4];
#pragma unroll
            for (int m = 0; m < 4; m++) {
                unsigned int x = 0;
#pragma unroll
                for (int k = 0; k < 4; k++)
                    x |= (unsigned int)tile[tc + m * 4 + k][dl] << (8 * k);
                w[m] = x;
            }
            *(i32x4*)&qt[(long)(d0 + dl) * S + t0 + tc] = *(i32x4*)w;
        }
    }
}

extern "C" void kernel_launch(void* const* d_in, const int* in_sizes, int n_in,
                              void* d_out, int out_size, void* d_ws, size_t ws_size,
                              hipStream_t stream) {
    (void)in_sizes; (void)n_in; (void)out_size;

    const float* classical = (const float*)d_in[0];
    const float* quantum   = (const float*)d_in[1];
    const float* Wc        = (const float*)d_in[2];
    const float* bc        = (const float*)d_in[3];
    const float* Wq        = (const float*)d_in[4];
    const float* bq        = (const float*)d_in[5];
    const float* Wg        = (const float*)d_in[6];
    const float* bg        = (const float*)d_in[7];
    const float* temp      = (const float*)d_in[8];
    float* out = (float*)d_out;

    const int B = 4, S = 2048, D = 1024;
    const long MD = (long)B * S * D;  // 8388608

    float* l    = (float*)d_ws;                    // B*S f32
    u16* Wc_b   = (u16*)(l + (long)B * S);         // D*D u16
    u16* Wq_b   = Wc_b + (long)D * D;              // D*D u16
    u8*  Wg8    = (u8*)(Wq_b + (long)D * D);       // D*2D bytes
    u16* cls_b  = (u16*)(Wg8 + (long)D * 2 * D);   // MD u16 (g overlay after proj)
    u16* qnt_b  = cls_b + MD;                      // MD u16
    u8*  cp8    = (u8*)(qnt_b + MD);               // MD bytes
    u8*  qp8    = cp8 + MD;                        // MD bytes
    u8*  qT8    = qp8 + MD;                        // MD bytes
    u8*  P8     = qT8 + MD;                        // B*CH*S bytes
    u16* g      = cls_b;                           // overlay: cls_b dead after proj

    const size_t fixed_bytes = (size_t)B * S * 4 + 2 * (size_t)D * D * 2 +
        (size_t)D * 2 * D + 2 * (size_t)MD * 2 + 3 * (size_t)MD;
    int CH = 128;
    for (int c = 2048; c >= 128; c >>= 1) {
        if (ws_size >= fixed_bytes + (size_t)B * c * S) { CH = c; break; }
    }
    const int chDiv  = CH / 128;
    const int nwgSim = (S / 128) * chDiv;  // per-z sim blocks, gx = 16

    dim3 blk(256);

    // 1) prep + quantum^T(fp8) fused
    prepT<<<4096, blk, 0, stream>>>(
        (const f32x4*)classical, (const f32x4*)quantum,
        (const f32x4*)Wc, (const f32x4*)Wq, (const f32x4*)Wg,
        (ushort4*)cls_b, (ushort4*)qnt_b,
        (ushort4*)Wc_b, (ushort4*)Wq_b, (unsigned int*)Wg8,
        (f32x4*)l, MD / 4, (long)D * D / 4, (long)D * 2 * D / 4, (long)B * S / 4,
        quantum, qT8, S, D);

    // 2) fused projections (z=2): {cp8,qp8} = fp8({cls,qnt}@{Wc,Wq}^T + {bc,bq})
    gemm_proj<<<dim3(D / 128, (B * S) / 128, 2), blk, 0, stream>>>(
        cls_b, qnt_b, D, Wc_b, (long)D * D, D, cp8, MD, D, D, bc, bq);

    // 3) gate + sim(chunk 0) fused:
    //    g = sigmoid([cp8|qp8]@Wg8^T + bg); P8 = fp8(exp(cp8@qp8^T/(32t))), l += rowsums
    gateSim<<<512 + B * nwgSim, blk, 0, stream>>>(
        cp8, qp8, Wg8, g, bg,
        P8, (long)CH * S, temp, l, S,
        (long)S * D, D, S, nwgSim);

    // 4) PV + merge (chunk 0): out = cls + g*(P8@qT8^T)/l
    gemm8<4><<<dim3(D / 128, chDiv, B), blk, 0, stream>>>(
        P8, nullptr, (long)CH * S, S, 1 << 30, qT8, (long)D * S, S,
        out, 0, (long)S * D, D, S,
        nullptr, nullptr, classical, g, l, S);

    // remaining chunks (only if CH < S)
    for (int m0 = CH; m0 < S; m0 += CH) {
        gemm8<2><<<dim3(S / 128, chDiv, B), blk, 0, stream>>>(
            cp8 + (long)m0 * D, nullptr, (long)S * D, D, 1 << 30,
            qp8, (long)S * D, D, P8, 0, (long)CH * S, S, D,
            nullptr, temp, nullptr, nullptr, l + m0, S);
        gemm8<4><<<dim3(D / 128, chDiv, B), blk, 0, stream>>>(
            P8, nullptr, (long)CH * S, S, 1 << 30, qT8, (long)D * S, S,
            out, (long)m0 * D, (long)S * D, D, S,
            nullptr, nullptr, classical, g, l + m0, S);
    }
}